// Round 1
// baseline (832.386 us; speedup 1.0000x reference)
//
#include <hip/hip_runtime.h>
#include <hip/hip_bf16.h>

#define NB 8
#define GX 256
#define GY 256
#define NPIX (GX*GY)      // 65536 pixels per batch
#define NC 64             // channels = H*D
#define NH 4
#define ND 16
#define HIN 16
#define HHID 64
#define CC (NC*NC)        // 4096
#define LN_EPS 1e-5f

#define BPB 128           // blocks per batch for pass kernels
#define PPB (NPIX/BPB)    // 512 pixels per block
#define CHUNK 16          // pixels staged per iteration

// ---------------- hypernetwork: w = (gelu(p@w1+b1))@w2 + b2 ----------------
__global__ void hyper_mlp_kernel(
    const float* __restrict__ p,
    const float* __restrict__ qw1, const float* __restrict__ qb1,
    const float* __restrict__ qw2, const float* __restrict__ qb2,
    const float* __restrict__ kw1, const float* __restrict__ kb1,
    const float* __restrict__ kw2, const float* __restrict__ kb2,
    const float* __restrict__ vw1, const float* __restrict__ vb1,
    const float* __restrict__ vw2, const float* __restrict__ vb2,
    float* __restrict__ wout)   // [3][NB][CC]
{
    const int proj = blockIdx.x;
    const int b    = blockIdx.y;
    const float* w1 = (proj == 0) ? qw1 : (proj == 1) ? kw1 : vw1;
    const float* b1 = (proj == 0) ? qb1 : (proj == 1) ? kb1 : vb1;
    const float* w2 = (proj == 0) ? qw2 : (proj == 1) ? kw2 : vw2;
    const float* b2 = (proj == 0) ? qb2 : (proj == 1) ? kb2 : vb2;

    __shared__ float hsh[HHID];
    const int t = threadIdx.x;
    if (t < HHID) {
        float a = b1[t];
        #pragma unroll
        for (int i = 0; i < HIN; ++i) a = fmaf(p[b*HIN + i], w1[i*HHID + t], a);
        // JAX default gelu (approximate=True, tanh form)
        float x3 = a * a * a;
        float inner = 0.7978845608028654f * (a + 0.044715f * x3);
        hsh[t] = 0.5f * a * (1.0f + tanhf(inner));
    }
    __syncthreads();
    #pragma unroll
    for (int r = 0; r < CC/256; ++r) {
        int o = t + 256*r;
        float a = b2[o];
        for (int j = 0; j < HHID; ++j) a = fmaf(hsh[j], w2[j*CC + o], a);
        wout[((size_t)proj*NB + b)*CC + o] = a;
    }
}

// ---------------- pass 1: K,V projection + LN + Xkv reduction ----------------
__global__ __launch_bounds__(256, 2) void kv_kernel(
    const float* __restrict__ X,      // [NB][NPIX][NC]
    const float* __restrict__ wgen,   // [3][NB][CC]
    const float* __restrict__ lnk_g,  // [NC]
    const float* __restrict__ lnk_b,  // [NC]
    float* __restrict__ xkv)          // [NB][NH*ND*ND] accumulated atomically
{
    const int bb = blockIdx.x, b = blockIdx.y;
    const int t = threadIdx.x, wave = t >> 6, lane = t & 63;

    // register-resident weight columns: lane c holds wk[:,c], wv[:,c]
    const float* wk = wgen + ((size_t)1*NB + b)*CC;
    const float* wv = wgen + ((size_t)2*NB + b)*CC;
    float wkc[NC], wvc[NC];
    #pragma unroll
    for (int j = 0; j < NC; ++j) { wkc[j] = wk[j*NC + lane]; wvc[j] = wv[j*NC + lane]; }
    const float g    = lnk_g[lane];
    const float beta = lnk_b[lane];

    float acc[ND];
    #pragma unroll
    for (int e = 0; e < ND; ++e) acc[e] = 0.f;

    __shared__ float xs[CHUNK*NC];      // 4 KB
    __shared__ float red[4][NC*ND];     // 16 KB

    const float* Xb = X + ((size_t)b*NPIX + (size_t)bb*PPB) * NC;

    for (int it = 0; it < PPB/CHUNK; ++it) {
        ((float4*)xs)[t] = ((const float4*)(Xb + (size_t)it*CHUNK*NC))[t];
        __syncthreads();
        #pragma unroll
        for (int pp = 0; pp < CHUNK/4; ++pp) {
            const float* xp = xs + (wave + pp*4)*NC;
            float k0=0.f,k1=0.f,k2=0.f,k3=0.f, v0=0.f,v1=0.f,v2=0.f,v3=0.f;
            #pragma unroll
            for (int j = 0; j < NC; j += 4) {
                const float4 x4 = *(const float4*)(xp + j);
                k0 = fmaf(x4.x, wkc[j+0], k0);
                k1 = fmaf(x4.y, wkc[j+1], k1);
                k2 = fmaf(x4.z, wkc[j+2], k2);
                k3 = fmaf(x4.w, wkc[j+3], k3);
                v0 = fmaf(x4.x, wvc[j+0], v0);
                v1 = fmaf(x4.y, wvc[j+1], v1);
                v2 = fmaf(x4.z, wvc[j+2], v2);
                v3 = fmaf(x4.w, wvc[j+3], v3);
            }
            float k = (k0+k1)+(k2+k3);
            float v = (v0+v1)+(v2+v3);
            // wave-wide LN stats over all 64 channels
            float sk = k, sv = v, skk = k*k, svv = v*v;
            #pragma unroll
            for (int off = 32; off >= 1; off >>= 1) {
                sk  += __shfl_xor(sk,  off);
                sv  += __shfl_xor(sv,  off);
                skk += __shfl_xor(skk, off);
                svv += __shfl_xor(svv, off);
            }
            const float mk = sk * (1.f/NC), mv = sv * (1.f/NC);
            const float rk = rsqrtf(skk*(1.f/NC) - mk*mk + LN_EPS);
            const float rv = rsqrtf(svv*(1.f/NC) - mv*mv + LN_EPS);
            // faithful to reference: BOTH k and v use lnk params
            const float kh = (k - mk)*rk*g + beta;
            const float vh = (v - mv)*rv*g + beta;
            // outer product: lane c=(h*16+d) accumulates Xkv[h][d][0..15]
            const int hbase = lane & 48;
            #pragma unroll
            for (int e = 0; e < ND; ++e) {
                float ve = __shfl(vh, hbase | e);
                acc[e] = fmaf(kh, ve, acc[e]);
            }
        }
        __syncthreads();
    }

    // block reduction across the 4 waves, then one atomicAdd per entry
    #pragma unroll
    for (int e = 0; e < ND; ++e) red[wave][lane*ND + e] = acc[e];
    __syncthreads();
    for (int idx = t; idx < NC*ND; idx += 256) {
        float s = red[0][idx] + red[1][idx] + red[2][idx] + red[3][idx];
        atomicAdd(&xkv[(size_t)b*NC*ND + idx], s);
    }
}

// ---------------- pass 2: Q projection + contraction with Xkv ----------------
__global__ __launch_bounds__(256, 2) void q_kernel(
    const float* __restrict__ X,      // [NB][NPIX][NC]
    const float* __restrict__ wgen,   // [3][NB][CC] (proj 0 = Q)
    const float* __restrict__ xkv,    // [NB][NH][ND][ND]
    float* __restrict__ out)          // [NB][NPIX][NC], channel = e*4+h
{
    const int bb = blockIdx.x, b = blockIdx.y;
    const int t = threadIdx.x, wave = t >> 6, lane = t & 63;

    const float* wq = wgen + (size_t)b*CC;
    float wqc[NC];
    #pragma unroll
    for (int j = 0; j < NC; ++j) wqc[j] = wq[j*NC + lane];

    // lane c emits output channel c: h=c&3, e=c>>2; preload Xkv[h][d][e]/N
    const int h = lane & 3, e = lane >> 2;
    float kvp[ND];
    #pragma unroll
    for (int d = 0; d < ND; ++d)
        kvp[d] = xkv[(size_t)b*NC*ND + (h*ND + d)*ND + e] * (1.f/(float)NPIX);

    __shared__ float xs[CHUNK*NC];
    const float* Xb = X   + ((size_t)b*NPIX + (size_t)bb*PPB) * NC;
    float*       Ob = out + ((size_t)b*NPIX + (size_t)bb*PPB) * NC;

    for (int it = 0; it < PPB/CHUNK; ++it) {
        ((float4*)xs)[t] = ((const float4*)(Xb + (size_t)it*CHUNK*NC))[t];
        __syncthreads();
        #pragma unroll
        for (int pp = 0; pp < CHUNK/4; ++pp) {
            const int p = wave + pp*4;
            const float* xp = xs + p*NC;
            float q0=0.f,q1=0.f,q2=0.f,q3=0.f;
            #pragma unroll
            for (int j = 0; j < NC; j += 4) {
                const float4 x4 = *(const float4*)(xp + j);
                q0 = fmaf(x4.x, wqc[j+0], q0);
                q1 = fmaf(x4.y, wqc[j+1], q1);
                q2 = fmaf(x4.z, wqc[j+2], q2);
                q3 = fmaf(x4.w, wqc[j+3], q3);
            }
            float q = (q0+q1)+(q2+q3);   // q for input-channel ordering h*16+d (lane index)
            // out[c=e*4+h] = sum_d q[h*16+d] * Xkv[h][d][e]
            float o = 0.f;
            const int qbase = (lane & 3) << 4;
            #pragma unroll
            for (int d = 0; d < ND; ++d) {
                float qd = __shfl(q, qbase | d);
                o = fmaf(qd, kvp[d], o);
            }
            Ob[(size_t)(it*CHUNK + p)*NC + lane] = o;
        }
        __syncthreads();
    }
}

extern "C" void kernel_launch(void* const* d_in, const int* in_sizes, int n_in,
                              void* d_out, int out_size, void* d_ws, size_t ws_size,
                              hipStream_t stream) {
    const float* X    = (const float*)d_in[0];
    const float* p    = (const float*)d_in[1];
    const float* qw1  = (const float*)d_in[2];
    const float* qb1  = (const float*)d_in[3];
    const float* qw2  = (const float*)d_in[4];
    const float* qb2  = (const float*)d_in[5];
    const float* kw1  = (const float*)d_in[6];
    const float* kb1  = (const float*)d_in[7];
    const float* kw2  = (const float*)d_in[8];
    const float* kb2  = (const float*)d_in[9];
    const float* vw1  = (const float*)d_in[10];
    const float* vb1  = (const float*)d_in[11];
    const float* vw2  = (const float*)d_in[12];
    const float* vb2  = (const float*)d_in[13];
    const float* lnkg = (const float*)d_in[14];
    const float* lnkb = (const float*)d_in[15];
    // d_in[16], d_in[17] (lnv_g, lnv_b) are unused by the reference.

    float* out  = (float*)d_out;
    float* wgen = (float*)d_ws;                    // [3][NB][CC] = 393 KB
    float* xkv  = wgen + (size_t)3*NB*CC;          // [NB][1024] = 32 KB

    hyper_mlp_kernel<<<dim3(3, NB), 256, 0, stream>>>(
        p, qw1,qb1,qw2,qb2, kw1,kb1,kw2,kb2, vw1,vb1,vw2,vb2, wgen);
    hipMemsetAsync(xkv, 0, (size_t)NB*NC*ND*sizeof(float), stream);
    kv_kernel<<<dim3(BPB, NB), 256, 0, stream>>>(X, wgen, lnkg, lnkb, xkv);
    q_kernel<<<dim3(BPB, NB), 256, 0, stream>>>(X, wgen, xkv, out);
}

// Round 2
// 139.914 us; speedup vs baseline: 5.9493x; 5.9493x over previous
//
#include <hip/hip_runtime.h>
#include <hip/hip_bf16.h>

typedef __attribute__((ext_vector_type(8))) short bf16x8;
typedef __attribute__((ext_vector_type(4))) float f32x4;

#define NB 8
#define NPIX 65536
#define NC 64
#define CC 4096
#define HIN 16
#define HHID 64
#define LN_EPS 1e-5f

static __device__ __forceinline__ short f2bf(float f) {
    union { __hip_bfloat16 h; short s; } u;
    u.h = __float2bfloat16(f);
    return u.s;
}

// ---------------- hypernetwork: w = (gelu(p@w1+b1))@w2 + b2 ----------------
// proj 0 (Q): store fp32 [b][cin][cout] for the fold kernel.
// proj 1 (K): store bf16 transposed wkvt[b][cout][cin]     (rows 0..63)
// proj 2 (V): store bf16 transposed wkvt[b][64+cout][cin]  (rows 64..127)
__global__ void hyper_mlp_kernel(
    const float* __restrict__ p,
    const float* __restrict__ qw1, const float* __restrict__ qb1,
    const float* __restrict__ qw2, const float* __restrict__ qb2,
    const float* __restrict__ kw1, const float* __restrict__ kb1,
    const float* __restrict__ kw2, const float* __restrict__ kb2,
    const float* __restrict__ vw1, const float* __restrict__ vb1,
    const float* __restrict__ vw2, const float* __restrict__ vb2,
    float* __restrict__ wq,     // [NB][CC] fp32
    short* __restrict__ wkvt)   // [NB][128][64] bf16 bits
{
    const int proj = blockIdx.x;
    const int b    = blockIdx.y;
    const float* w1 = (proj == 0) ? qw1 : (proj == 1) ? kw1 : vw1;
    const float* b1 = (proj == 0) ? qb1 : (proj == 1) ? kb1 : vb1;
    const float* w2 = (proj == 0) ? qw2 : (proj == 1) ? kw2 : vw2;
    const float* b2 = (proj == 0) ? qb2 : (proj == 1) ? kb2 : vb2;

    __shared__ float hsh[HHID];
    const int t = threadIdx.x;
    if (t < HHID) {
        float a = b1[t];
        #pragma unroll
        for (int i = 0; i < HIN; ++i) a = fmaf(p[b*HIN + i], w1[i*HHID + t], a);
        float x3 = a * a * a;
        float inner = 0.7978845608028654f * (a + 0.044715f * x3);
        hsh[t] = 0.5f * a * (1.0f + tanhf(inner));
    }
    __syncthreads();
    #pragma unroll
    for (int r = 0; r < CC/256; ++r) {
        int o = t + 256*r;              // o = cin*64 + cout
        float a = b2[o];
        for (int j = 0; j < HHID; ++j) a = fmaf(hsh[j], w2[j*CC + o], a);
        int cin = o >> 6, cout = o & 63;
        if (proj == 0) {
            wq[(size_t)b*CC + o] = a;
        } else {
            int row = (proj == 1) ? cout : 64 + cout;
            wkvt[((size_t)b*128 + row)*64 + cin] = f2bf(a);
        }
    }
}

// -------- fold: W~[cin][e*4+h] = sum_d Wq[cin][h*16+d] * Xkv[h][d][e] / NPIX --------
__global__ void fold_kernel(const float* __restrict__ wq,
                            const float* __restrict__ xkv,
                            short* __restrict__ wft)   // [NB][64 och][64 cin] bf16
{
    const int b = blockIdx.x, t = threadIdx.x;
    #pragma unroll
    for (int i = 0; i < 16; ++i) {
        int idx = t + 256*i;            // 4096 outputs
        int och = idx >> 6, c = idx & 63;
        int h = och & 3, e = och >> 2;
        float s = 0.f;
        #pragma unroll
        for (int d = 0; d < 16; ++d)
            s += wq[(size_t)b*CC + c*64 + h*16 + d] * xkv[(size_t)b*1024 + h*256 + d*16 + e];
        wft[((size_t)b*64 + och)*64 + c] = f2bf(s * (1.f/65536.f));
    }
}

// ---------------- pass 1: K,V projection (MFMA) + LN + Xkv (MFMA) ----------------
__global__ __launch_bounds__(256, 2) void kv_kernel(
    const float* __restrict__ X,      // [NB][NPIX][64]
    const short* __restrict__ wkvt,   // [NB][128][64] bf16
    const float* __restrict__ lnk_g,
    const float* __restrict__ lnk_b,
    float* __restrict__ xkv)          // [NB][4][16][16] fp32, atomically accumulated
{
    const int bb = blockIdx.x, b = blockIdx.y;      // 64 blocks per batch
    const int t = threadIdx.x, wave = t >> 6, lane = t & 63;
    const int l4 = lane >> 4, l15 = lane & 15;

    // B-frags: b[j] = Wkv[cin = s*32 + l4*8 + j][och = nt*16 + l15]
    bf16x8 bw[2][8];
    #pragma unroll
    for (int s = 0; s < 2; ++s)
        #pragma unroll
        for (int nt = 0; nt < 8; ++nt) {
            const short* pw = wkvt + (((size_t)b*128 + nt*16 + l15)*64 + s*32 + l4*8);
            bw[s][nt] = *(const bf16x8*)pw;
        }

    float g[4], be[4];
    #pragma unroll
    for (int nt = 0; nt < 4; ++nt) {
        g[nt]  = lnk_g[nt*16 + l15];
        be[nt] = lnk_b[nt*16 + l15];
    }

    f32x4 kv[4];
    #pragma unroll
    for (int h = 0; h < 4; ++h) kv[h] = (f32x4){0.f,0.f,0.f,0.f};

    const float* Xw = X + ((size_t)b*NPIX + (size_t)bb*1024 + wave*256)*64;

    for (int ch = 0; ch < 8; ++ch) {                // 8 chunks x 32 pixels
        const float* Xc = Xw + (size_t)ch*32*64;
        // load A-tiles: lane reads X[tile*16 + l15][s*32 + l4*8 .. +8]
        float xf[2][2][8];
        #pragma unroll
        for (int t2 = 0; t2 < 2; ++t2)
            #pragma unroll
            for (int s = 0; s < 2; ++s) {
                const float* px = Xc + (t2*16 + l15)*64 + s*32 + l4*8;
                *(float4*)&xf[t2][s][0] = *(const float4*)px;
                *(float4*)&xf[t2][s][4] = *(const float4*)(px + 4);
            }
        bf16x8 af[2][2];
        #pragma unroll
        for (int t2 = 0; t2 < 2; ++t2)
            #pragma unroll
            for (int s = 0; s < 2; ++s)
                #pragma unroll
                for (int j = 0; j < 8; ++j) af[t2][s][j] = f2bf(xf[t2][s][j]);

        f32x4 acc[2][8];
        #pragma unroll
        for (int t2 = 0; t2 < 2; ++t2)
            #pragma unroll
            for (int nt = 0; nt < 8; ++nt) acc[t2][nt] = (f32x4){0.f,0.f,0.f,0.f};
        #pragma unroll
        for (int s = 0; s < 2; ++s)
            #pragma unroll
            for (int t2 = 0; t2 < 2; ++t2)
                #pragma unroll
                for (int nt = 0; nt < 8; ++nt)
                    acc[t2][nt] = __builtin_amdgcn_mfma_f32_16x16x32_bf16(
                        af[t2][s], bw[s][nt], acc[t2][nt], 0, 0, 0);

        // LN over 64 channels per pixel; build Xkv fragments (free transpose:
        // K-dim slot j corresponds to pixel 16*(j>>2) + 4*l4 + (j&3), so
        // frag elem j is this lane's own acc value [tile=j>>2][reg=j&3]).
        bf16x8 ka[4], va[4];
        #pragma unroll
        for (int t2 = 0; t2 < 2; ++t2) {
            float sk[4], qk[4], sv[4], qv[4];
            #pragma unroll
            for (int r = 0; r < 4; ++r) {
                float a0 = acc[t2][0][r], a1 = acc[t2][1][r], a2 = acc[t2][2][r], a3 = acc[t2][3][r];
                float b0 = acc[t2][4][r], b1 = acc[t2][5][r], b2 = acc[t2][6][r], b3 = acc[t2][7][r];
                sk[r] = (a0+a1)+(a2+a3);
                qk[r] = (a0*a0+a1*a1)+(a2*a2+a3*a3);
                sv[r] = (b0+b1)+(b2+b3);
                qv[r] = (b0*b0+b1*b1)+(b2*b2+b3*b3);
            }
            #pragma unroll
            for (int r = 0; r < 4; ++r) {
                #pragma unroll
                for (int off = 1; off < 16; off <<= 1) {
                    sk[r] += __shfl_xor(sk[r], off);
                    qk[r] += __shfl_xor(qk[r], off);
                    sv[r] += __shfl_xor(sv[r], off);
                    qv[r] += __shfl_xor(qv[r], off);
                }
            }
            #pragma unroll
            for (int r = 0; r < 4; ++r) {
                float mk = sk[r]*(1.f/NC);
                float rk = rsqrtf(qk[r]*(1.f/NC) - mk*mk + LN_EPS);
                float mv = sv[r]*(1.f/NC);
                float rv = rsqrtf(qv[r]*(1.f/NC) - mv*mv + LN_EPS);
                #pragma unroll
                for (int nt = 0; nt < 4; ++nt) {
                    // faithful: BOTH k and v normalized with lnk params
                    ka[nt][t2*4+r] = f2bf((acc[t2][nt  ][r] - mk)*rk*g[nt] + be[nt]);
                    va[nt][t2*4+r] = f2bf((acc[t2][nt+4][r] - mv)*rv*g[nt] + be[nt]);
                }
            }
        }
        #pragma unroll
        for (int h = 0; h < 4; ++h)
            kv[h] = __builtin_amdgcn_mfma_f32_16x16x32_bf16(ka[h], va[h], kv[h], 0, 0, 0);
    }

    // cross-wave reduction + one atomicAdd per entry
    __shared__ float red[4][1024];
    #pragma unroll
    for (int h = 0; h < 4; ++h)
        #pragma unroll
        for (int r = 0; r < 4; ++r)
            red[wave][(h*4+r)*64 + lane] = kv[h][r];
    __syncthreads();
    for (int idx = t; idx < 1024; idx += 256) {
        float s = red[0][idx] + red[1][idx] + red[2][idx] + red[3][idx];
        int ln = idx & 63, hr = idx >> 6;
        int h = hr >> 2, r = hr & 3;
        int d = (ln >> 4)*4 + r, e = ln & 15;
        atomicAdd(&xkv[(size_t)b*1024 + h*256 + d*16 + e], s);
    }
}

// ---------------- pass 2: out = X · W~  (Q projection folded with Xkv) ----------------
__global__ __launch_bounds__(256, 4) void q_kernel(
    const float* __restrict__ X,     // [NB][NPIX][64]
    const short* __restrict__ wft,   // [NB][64][64] bf16 (transposed: [och][cin])
    float* __restrict__ out)         // [NB][NPIX][64]
{
    const int bb = blockIdx.x, b = blockIdx.y;
    const int t = threadIdx.x, wave = t >> 6, lane = t & 63;
    const int l4 = lane >> 4, l15 = lane & 15;

    bf16x8 bw[2][4];
    #pragma unroll
    for (int s = 0; s < 2; ++s)
        #pragma unroll
        for (int nt = 0; nt < 4; ++nt) {
            const short* pw = wft + (((size_t)b*64 + nt*16 + l15)*64 + s*32 + l4*8);
            bw[s][nt] = *(const bf16x8*)pw;
        }

    const size_t pixbase = (size_t)b*NPIX + (size_t)bb*1024 + wave*256;
    const float* Xw = X + pixbase*64;
    float* Ob = out + pixbase*64;

    for (int tp = 0; tp < 8; ++tp) {                 // 2 tiles (32 px) per iter
        float xf[2][2][8];
        #pragma unroll
        for (int t2 = 0; t2 < 2; ++t2)
            #pragma unroll
            for (int s = 0; s < 2; ++s) {
                const float* px = Xw + (size_t)(tp*32 + t2*16 + l15)*64 + s*32 + l4*8;
                *(float4*)&xf[t2][s][0] = *(const float4*)px;
                *(float4*)&xf[t2][s][4] = *(const float4*)(px + 4);
            }
        #pragma unroll
        for (int t2 = 0; t2 < 2; ++t2) {
            bf16x8 af[2];
            #pragma unroll
            for (int s = 0; s < 2; ++s)
                #pragma unroll
                for (int j = 0; j < 8; ++j) af[s][j] = f2bf(xf[t2][s][j]);
            f32x4 acc[4];
            #pragma unroll
            for (int nt = 0; nt < 4; ++nt) acc[nt] = (f32x4){0.f,0.f,0.f,0.f};
            #pragma unroll
            for (int s = 0; s < 2; ++s)
                #pragma unroll
                for (int nt = 0; nt < 4; ++nt)
                    acc[nt] = __builtin_amdgcn_mfma_f32_16x16x32_bf16(
                        af[s], bw[s][nt], acc[nt], 0, 0, 0);
            #pragma unroll
            for (int nt = 0; nt < 4; ++nt)
                #pragma unroll
                for (int r = 0; r < 4; ++r)
                    Ob[(size_t)(tp*32 + t2*16 + l4*4 + r)*64 + nt*16 + l15] = acc[nt][r];
        }
    }
}

extern "C" void kernel_launch(void* const* d_in, const int* in_sizes, int n_in,
                              void* d_out, int out_size, void* d_ws, size_t ws_size,
                              hipStream_t stream) {
    const float* X    = (const float*)d_in[0];
    const float* p    = (const float*)d_in[1];
    const float* qw1  = (const float*)d_in[2];
    const float* qb1  = (const float*)d_in[3];
    const float* qw2  = (const float*)d_in[4];
    const float* qb2  = (const float*)d_in[5];
    const float* kw1  = (const float*)d_in[6];
    const float* kb1  = (const float*)d_in[7];
    const float* kw2  = (const float*)d_in[8];
    const float* kb2  = (const float*)d_in[9];
    const float* vw1  = (const float*)d_in[10];
    const float* vb1  = (const float*)d_in[11];
    const float* vw2  = (const float*)d_in[12];
    const float* vb2  = (const float*)d_in[13];
    const float* lnkg = (const float*)d_in[14];
    const float* lnkb = (const float*)d_in[15];

    float* out  = (float*)d_out;
    float* wq   = (float*)d_ws;                       // NB*CC fp32
    float* xkv  = wq + (size_t)NB*CC;                 // NB*1024 fp32
    short* wkvt = (short*)(xkv + (size_t)NB*1024);    // NB*128*64 bf16
    short* wft  = wkvt + (size_t)NB*128*64;           // NB*64*64 bf16

    hyper_mlp_kernel<<<dim3(3, NB), 256, 0, stream>>>(
        p, qw1,qb1,qw2,qb2, kw1,kb1,kw2,kb2, vw1,vb1,vw2,vb2, wq, wkvt);
    hipMemsetAsync(xkv, 0, (size_t)NB*1024*sizeof(float), stream);
    kv_kernel<<<dim3(64, NB), 256, 0, stream>>>(X, wkvt, lnkg, lnkb, xkv);
    fold_kernel<<<NB, 256, 0, stream>>>(wq, xkv, wft);
    q_kernel<<<dim3(64, NB), 256, 0, stream>>>(X, wft, out);
}